// Round 20
// baseline (279.932 us; speedup 1.0000x reference)
//
#include <hip/hip_runtime.h>

typedef unsigned short u16;
typedef unsigned int u32;
typedef unsigned long long u64;

typedef __attribute__((ext_vector_type(8))) short short8;   // 8 bf16 = 4 VGPRs
typedef __attribute__((ext_vector_type(4))) float floatx4;  // MFMA accumulator

__device__ __forceinline__ float b2f(u16 h) {
  u32 u = ((u32)h) << 16;
  return __builtin_bit_cast(float, u);
}
__device__ __forceinline__ u16 f2b(float f) {
  u32 u = __builtin_bit_cast(u32, f);
  u32 r = 0x7FFFu + ((u >> 16) & 1u);  // RNE
  return (u16)((u + r) >> 16);
}

// async global->LDS, 16B per lane. LDS dest = wave-uniform base + lane*16.
__device__ __forceinline__ void gl_lds16(const void* g, void* l) {
  __builtin_amdgcn_global_load_lds(
      (__attribute__((address_space(1))) void*)(u64)g,
      (__attribute__((address_space(3))) void*)(u32)(u64)l, 16, 0, 0);
}

enum { EPI_PHI_BIAS = 0, EPI_BIAS = 1, EPI_NONE = 2,
       EPI_ZBIAS_F32 = 3 };

// ==================== 256x256 kernel (ALL GEMMs) =============================
// R10-best structure: 256x256 tile, 8 waves (2M x 4N, 128x64 each, acc[8][4]),
// BK=64 K-tiles, 128B-contiguous staging rows, 2 x 64KB LDS buffers, 2 kstep/
// tile, one barrier per tile. (acc 128 regs + ~124 arch regs -> 2 waves/SIMD
// hard cap -> 1 block/CU is register-forced; schedule variants R9-R13 all
// null because no co-resident block can cover the barrier drains.)
// A_F32 (R14, R16): fp32->bf16 conversion fused into A-staging (no standalone
// fcvt passes). Depth-1 register prefetch, SINGLE rA set; packA AFTER
// kstep(kk1) so the 8 rA loads get ~2500cy of MFMA cover (R17: 67->62us).
// R18 (KSUM): ksum_rows fused into the K-proj TRANS_OUT store pass (32-lane
// group shfl reduce + 1 atomicAdd per dloc; Ksum zeroed by wconv).
// R19 (ZDEN): zden fused into Q-proj epilogue (row-strip shfl reduce + 4
// atomics/row into Zraw); final GEMM computes 1/(Zraw+1e-6) inline.
// R20 (DUAL): K-proj and V-proj merged into ONE dispatch (grid z=2; bz=1
// selects {A2,B2,bias2,C2}, phi off, ksum off — runtime wave-uniform selects,
// R0's proven pattern). Kills one dispatch boundary/tail and one template
// instantiation (rule #19 regalloc perturbation).
// LDS layout per matrix: 256 rows x 8 chunks of 16B, phys_chunk = c ^ (r&7);
// staging slot j: R=j>>3, c=(j&7)^(R&7); fragment reads ra*128+((q^(ra&7))*16),
// kk=1 = ^64 (uniform bank spread).
// Split-K / batch: abz = bz & abmask; kbase = (bz >> kshift) * K.
// B batched via sBb (final GEMM: G' = [4][1024][1024]).
// TRANS_OUT epilogue: two 128-col passes through sT[128][264] (fits LDS).
template<int EPI, bool TRANS_OUT, bool A_F32, bool KSUM, bool ZDEN, bool DUAL>
__global__ __launch_bounds__(512, 2)
void gemm_bt256(const void* __restrict__ Ap, const u16* __restrict__ Bp0,
                const float* __restrict__ bias, const float* __restrict__ Zall,
                void* __restrict__ Cp,
                int M, int N, int K, int ldA, int ldB, int ldC,
                long sAb, long sBb, long sCb, long sZb, int abmask, int kshift,
                const void* __restrict__ Ap2, const u16* __restrict__ Bp2,
                const float* __restrict__ bias2, void* __restrict__ Cp2)
{
  constexpr int TSTRIDE = 65536;                  // one K-tile buffer (A+B)
  constexpr int BOFF    = 32768;                  // B tile offset within buffer
  __shared__ char smem[2 * TSTRIDE];              // 128 KB -> 1 block/CU

  const int tid  = threadIdx.x;
  const int lane = tid & 63;
  const int wave = tid >> 6;
  const int wm = wave >> 2, wn = wave & 3;   // 2x4 waves, 128x64 each
  const int fl = lane & 15;
  const int q  = lane >> 4;
  const int r4 = q * 4;
  const int bm0 = blockIdx.x * 256, bn0 = blockIdx.y * 256;
  const int bz = blockIdx.z;
  const int abz = bz & abmask;
  const int kbase = (bz >> kshift) * K;

  const void* Asel = Ap; const u16* Bsel = Bp0;
  const float* biasSel = bias; void* Csel = Cp;
  bool phi_on = true, do_ksum = true;
  if constexpr (DUAL) {
    if (bz) { Asel = Ap2; Bsel = Bp2; biasSel = bias2; Csel = Cp2;
              phi_on = false; do_ksum = false; }
  }

  const u16*   Ah = (const u16*)Asel   + (size_t)abz * sAb + kbase;
  const float* Af = (const float*)Asel + (size_t)abz * sAb + kbase;
  const u16*   Bh = Bsel + (size_t)abz * sBb + kbase;

  // staging: per matrix 2048 16B LDS slots (256 rows x 8 swizzled chunks).
  const u16* gA[4]; const float* gAf[4]; const u16* gB[4]; int sL[4], dL[4];
  #pragma unroll
  for (int n = 0; n < 4; ++n) {
    int j = n * 512 + tid;                   // physical 16B slot
    int R = j >> 3, c = (j & 7) ^ (R & 7);
    if constexpr (A_F32) gAf[n] = Af + (size_t)(bm0 + R) * ldA + c * 8;
    else                 gA[n]  = Ah + (size_t)(bm0 + R) * ldA + c * 8;
    gB[n] = Bh + (size_t)(bn0 + R) * ldB + c * 8;
    sL[n] = (n * 512 + wave * 64) * 16;      // wave-uniform base (gl_lds)
    dL[n] = j * 16;                          // per-thread ds_write dest
  }

  // fragment LDS byte offsets (kk=0; kk=1 = ^64)
  int aoff[8], boff[4];
  #pragma unroll
  for (int i = 0; i < 8; ++i) {
    int ra = wm * 128 + i * 16 + fl;
    aoff[i] = ra * 128 + ((q ^ (ra & 7)) * 16);
  }
  #pragma unroll
  for (int i = 0; i < 4; ++i) {
    int rb = wn * 64 + i * 16 + fl;
    boff[i] = rb * 128 + ((q ^ (rb & 7)) * 16);
  }

  floatx4 zero = {0.f, 0.f, 0.f, 0.f};
  floatx4 acc[8][4];
  #pragma unroll
  for (int i = 0; i < 8; ++i)
    #pragma unroll
    for (int j = 0; j < 4; ++j) acc[i][j] = zero;

  auto stageB = [&](int t, char* base) {     // 4 gl_lds16, 128B rows
    #pragma unroll
    for (int n = 0; n < 4; ++n) gl_lds16(gB[n] + t * 64, base + BOFF + sL[n]);
  };
  auto stageA_dma = [&](int t, char* base) { // bf16-A path
    #pragma unroll
    for (int n = 0; n < 4; ++n) gl_lds16(gA[n] + t * 64, base + sL[n]);
  };

  float4 rA[8];                              // fp32-A path: in-flight A rows
  auto loadA = [&](int t) {
    #pragma unroll
    for (int n = 0; n < 4; ++n) {
      rA[2 * n]     = *(const float4*)(gAf[n] + t * 64);
      rA[2 * n + 1] = *(const float4*)(gAf[n] + t * 64 + 4);
    }
  };
  auto packA = [&](char* base) {             // truncate-pack (R1-proven)
    #pragma unroll
    for (int n = 0; n < 4; ++n) {
      const u32* xb = (const u32*)&rA[2 * n];
      const u32* yb = (const u32*)&rA[2 * n + 1];
      union { u32 w[4]; short8 s; } cv;
      cv.w[0] = __builtin_amdgcn_perm(xb[1], xb[0], 0x07060302u);
      cv.w[1] = __builtin_amdgcn_perm(xb[3], xb[2], 0x07060302u);
      cv.w[2] = __builtin_amdgcn_perm(yb[1], yb[0], 0x07060302u);
      cv.w[3] = __builtin_amdgcn_perm(yb[3], yb[2], 0x07060302u);
      *(short8*)(base + dL[n]) = cv.s;
    }
  };

  auto kstep = [&](const char* bufc, int xo) {  // xo = 0 (kk=0) or 64 (kk=1)
    short8 bF[4], aF[8];
    #pragma unroll
    for (int i = 0; i < 4; ++i) bF[i] = *(const short8*)(bufc + BOFF + (boff[i] ^ xo));
    #pragma unroll
    for (int i = 0; i < 8; ++i) aF[i] = *(const short8*)(bufc + (aoff[i] ^ xo));
    __builtin_amdgcn_s_setprio(1);
    #pragma unroll
    for (int mi = 0; mi < 8; ++mi)
      #pragma unroll
      for (int ni = 0; ni < 4; ++ni)
        acc[mi][ni] = __builtin_amdgcn_mfma_f32_16x16x32_bf16(
            aF[mi], bF[ni], acc[mi][ni], 0, 0, 0);
    __builtin_amdgcn_s_setprio(0);
  };

  const int NT = K >> 6;                     // 16 (K=1024) or 4 (G, K=256)
  if constexpr (A_F32) {
    loadA(0); stageB(0, smem);
    asm volatile("s_waitcnt vmcnt(4)" ::: "memory");   // 8 A loads (oldest)
    packA(smem);
    asm volatile("s_waitcnt vmcnt(0) lgkmcnt(0)\ns_barrier" ::: "memory");
    int cur = 0;
    for (int t = 0; t < NT; ++t) {
      const bool pf = t + 1 < NT;
      const char* bufc = smem + cur;
      char* bufn = smem + (cur ^ TSTRIDE);
      if (pf) { loadA(t + 1); stageB(t + 1, bufn); }
      kstep(bufc, 0);
      kstep(bufc, 64);
      if (pf) {
        packA(bufn);                         // rA covered by both ksteps
        asm volatile("s_waitcnt vmcnt(0) lgkmcnt(0)\ns_barrier" ::: "memory");
      }
      cur ^= TSTRIDE;
    }
  } else {
    stageA_dma(0, smem); stageB(0, smem);
    asm volatile("s_waitcnt vmcnt(0)\ns_barrier" ::: "memory");
    int cur = 0;
    for (int t = 0; t < NT; ++t) {
      if (t + 1 < NT) {
        stageA_dma(t + 1, smem + (cur ^ TSTRIDE));
        stageB(t + 1, smem + (cur ^ TSTRIDE));
      }
      const char* bufc = smem + cur;
      kstep(bufc, 0);
      kstep(bufc, 64);
      if (t + 1 < NT)
        asm volatile("s_waitcnt vmcnt(0) lgkmcnt(0)\ns_barrier" ::: "memory");
      cur ^= TSTRIDE;
    }
  }

  if constexpr (!TRANS_OUT) {
    float ksc[4];                            // ZDEN: Ksum[col] per ni (L2-hot)
    if constexpr (ZDEN) {
      #pragma unroll
      for (int ni = 0; ni < 4; ++ni)
        ksc[ni] = Zall[bn0 + wn * 64 + ni * 16 + fl];   // Zall = Ksum here
    }
    #pragma unroll
    for (int mi = 0; mi < 8; ++mi) {
      #pragma unroll
      for (int r = 0; r < 4; ++r) {
        int row = bm0 + wm * 128 + mi * 16 + r4 + r;
        float zv = 0.f, zs = 0.f;
        if constexpr (EPI == EPI_ZBIAS_F32)
          zv = 1.0f / (Zall[(size_t)abz * sZb + row] + 1e-6f);
        #pragma unroll
        for (int ni = 0; ni < 4; ++ni) {
          int col = bn0 + wn * 64 + ni * 16 + fl;
          float vv = acc[mi][ni][r];
          if constexpr (EPI == EPI_PHI_BIAS) {
            vv += biasSel[col];
            if (phi_on) vv = __expf(-0.5f * vv * vv);
          }
          if constexpr (EPI == EPI_ZBIAS_F32) {
            ((float*)Csel)[(size_t)bz * sCb + (size_t)row * ldC + col] =
                vv * zv + biasSel[col];
          } else {
            ((u16*)Csel)[(size_t)bz * sCb + (size_t)row * ldC + col] = f2b(vv);
          }
          if constexpr (ZDEN) zs += vv * ksc[ni];
        }
        if constexpr (ZDEN) {
          #pragma unroll
          for (int off = 1; off < 16; off <<= 1)
            zs += __shfl_xor(zs, off, 64);   // within 16-lane row group
          if (fl == 0)
            atomicAdd((float*)&Zall[4096 + row], zs);  // Zraw = Ksum+4096
        }
      }
    }
  } else {
    // two passes of 128 d-cols through sT[128][264]; coalesced 16B stores
    // into C = [4][N(d)][4096(t)] bf16 (256-row tile never crosses a batch).
    u16* sT = (u16*)smem;                    // 128*264*2 = 67584 <= 128K
    #pragma unroll
    for (int p = 0; p < 2; ++p) {
      __syncthreads();                       // p=0: drains K-loop (all cnts)
      if ((wn >> 1) == p) {
        #pragma unroll
        for (int mi = 0; mi < 8; ++mi) {
          #pragma unroll
          for (int ni = 0; ni < 4; ++ni) {
            int colL = wn * 64 + ni * 16 + fl;       // in [p*128, p*128+128)
            int row0 = wm * 128 + mi * 16 + r4;
            float bcol = biasSel[bn0 + colL];
            ushort4 h;
            #pragma unroll
            for (int r = 0; r < 4; ++r) {
              float vv = acc[mi][ni][r] + bcol;
              if constexpr (EPI == EPI_PHI_BIAS)
                if (phi_on) vv = __expf(-0.5f * vv * vv);
              ((u16*)&h)[r] = f2b(vv);
            }
            *(ushort4*)(sT + (colL - p * 128) * 264 + row0) = h;
          }
        }
      }
      __syncthreads();
      #pragma unroll
      for (int i = 0; i < 8; ++i) {
        int c = tid + i * 512;               // 4096 x 16B chunks
        int dloc = c >> 5, t8 = (c & 31) * 8;
        int4 vv = *(const int4*)(sT + dloc * 264 + t8);
        int gd = bn0 + p * 128 + dloc;
        int gt = bm0 + t8;
        int batch = gt >> 12, tt = gt & 4095;
        *(int4*)((u16*)Csel + ((size_t)batch * N + gd) * 4096 + tt) = vv;
        if constexpr (KSUM) {
          if (do_ksum) {
            // fused ksum: chunk sum -> 32-lane-group reduce -> one atomicAdd.
            const u16* hh = (const u16*)&vv;
            float s8 = 0.f;
            #pragma unroll
            for (int j = 0; j < 8; ++j) s8 += b2f(hh[j]);
            #pragma unroll
            for (int off = 1; off < 32; off <<= 1)
              s8 += __shfl_xor(s8, off, 64); // offs<32: stays in 32-lane half
            if ((lane & 31) == 0)
              atomicAdd((float*)&Zall[(size_t)batch * 1024 + gd], s8);
          }
        }
      }
    }
  }
}

// weights -> bf16; also zero Ksum[4096] + Zraw[16384] (f32) for fused passes.
__global__ __launch_bounds__(256)
void wconv(const float* __restrict__ w0, const float* __restrict__ w1,
           const float* __restrict__ w2, const float* __restrict__ w3,
           u16* __restrict__ dst, float* __restrict__ Ksum) {
  unsigned e = blockIdx.x * 256 + threadIdx.x;
  if (e < 4096) Ksum[e] = 0.f;
  if (e < 16384) Ksum[4096 + e] = 0.f;       // Zraw
  int mat = e >> 18;
  size_t off = (size_t)(e & 262143) * 4;
  const float* src = mat == 0 ? w0 : mat == 1 ? w1 : mat == 2 ? w2 : w3;
  float4 v = *(const float4*)(src + off);
  ushort4 h;
  h.x = f2b(v.x); h.y = f2b(v.y); h.z = f2b(v.z); h.w = f2b(v.w);
  *(ushort4*)(dst + (size_t)mat * 1048576 + off) = h;
}

// out[i] = round(sum over 4 K-slices of bf16 partials), 4M elems, slice stride 4M
__global__ __launch_bounds__(256)
void reduce4(const u16* __restrict__ P, u16* __restrict__ out) {
  size_t i = ((size_t)blockIdx.x * 256 + threadIdx.x) * 8;
  int4 a = *(const int4*)(P + i);
  int4 b = *(const int4*)(P + i + 4194304);
  int4 c = *(const int4*)(P + i + 8388608);
  int4 d = *(const int4*)(P + i + 12582912);
  const u16* ha = (const u16*)&a; const u16* hb = (const u16*)&b;
  const u16* hc = (const u16*)&c; const u16* hd = (const u16*)&d;
  ushort4 o0, o1;
  #pragma unroll
  for (int j = 0; j < 8; ++j) {
    float s = b2f(ha[j]) + b2f(hb[j]) + b2f(hc[j]) + b2f(hd[j]);
    ((u16*)(j < 4 ? &o0 : &o1))[j & 3] = f2b(s);
  }
  *(ushort4*)(out + i) = o0;
  *(ushort4*)(out + i + 4) = o1;
}

extern "C" void kernel_launch(void* const* d_in, const int* in_sizes, int n_in,
                              void* d_out, int out_size, void* d_ws, size_t ws_size,
                              hipStream_t stream) {
  const float* q  = (const float*)d_in[0];
  const float* k  = (const float*)d_in[1];
  const float* v  = (const float*)d_in[2];
  const float* Wq = (const float*)d_in[3];
  const float* bq = (const float*)d_in[4];
  const float* Wk = (const float*)d_in[5];
  const float* bk = (const float*)d_in[6];
  const float* Wv = (const float*)d_in[7];
  const float* bv = (const float*)d_in[8];
  const float* Wo = (const float*)d_in[9];
  const float* bo = (const float*)d_in[10];
  float* out = (float*)d_out;

  // workspace layout (~112.1 MiB), aliasing chain (stream-ordered):
  u16* Wqb = (u16*)d_ws;                 // 4x 1024x1024 bf16 = 8 MiB
  u16* Wkb = Wqb + 1048576;
  u16* Wvb = Wkb + 1048576;
  u16* Wob = Wvb + 1048576;
  u16* Qb  = Wob + 1048576;              // [16384][1024] bf16, 32 MiB
  u16* KT  = Qb  + 16777216;             // [4][1024][4096] bf16, 32 MiB
  u16* VT  = KT  + 16777216;             // [4][1024][4096] bf16, 32 MiB
  u16* KVr = VT  + 16777216;             // [4][1024(d)][1024(l)] bf16, 8 MiB
  float* Ksum = (float*)(KVr + 4194304); // [4][1024] f32; Zraw = Ksum+4096
  // region reuse (each write strictly after the prior reader finishes):
  u16* Pkv = Qb;   // S2 split-K partials; dead after its reduce4 (Qproj later)
  u16* Pg  = VT;   // G split-K partials (VT dead after S2)
  u16* Gp  = KT;   // G' [4][1024(n)][1024(d)] (KT dead after S2)

  // 1. weights -> bf16 + Ksum/Zraw zero-init
  wconv<<<4096, 256, 0, stream>>>(Wq, Wk, Wv, Wo, Wqb, Ksum);

  // 2. K+V projections in ONE dispatch (z: 0=K phi+ksum, 1=V linear).
  dim3 gkv(64, 4, 2);
  gemm_bt256<EPI_PHI_BIAS, true, true, true, false, true><<<gkv, 512, 0, stream>>>(
      k, Wkb, bk, Ksum, KT, 16384, 1024, 1024, 1024, 1024, 0,
      0, 0, 0, 0, 0, 2, v, Wvb, bv, VT);

  // 3. S2: KVr[d,l] = sum_t KT[d,t]*VT[l,t], split-K x4 (z = kslice*4+batch)
  dim3 g2(4, 4, 16);
  gemm_bt256<EPI_NONE, false, false, false, false, false><<<g2, 512, 0, stream>>>(
      KT, VT, nullptr, nullptr, Pkv, 1024, 1024, 1024, 4096, 4096, 1024,
      4194304L, 4194304L, 1048576L, 0, 3, 2,
      nullptr, nullptr, nullptr, nullptr);
  reduce4<<<2048, 256, 0, stream>>>(Pkv, KVr);

  // 4. G'[n,d] = sum_l Wob[n,l]*KVr[d,l], split-K x4 (K=256/slice)
  dim3 gg(4, 4, 16);
  gemm_bt256<EPI_NONE, false, false, false, false, false><<<gg, 512, 0, stream>>>(
      Wob, KVr, nullptr, nullptr, Pg, 1024, 1024, 256, 1024, 1024, 1024,
      0L, 1048576L, 1048576L, 0, 3, 2,
      nullptr, nullptr, nullptr, nullptr);
  reduce4<<<2048, 256, 0, stream>>>(Pg, Gp);

  // 5. Q projection (fp32-A fused; ZDEN fused: zs(row) atomics into Zraw;
  //    Ksum complete — K+V dispatch stream-ordered earlier).
  dim3 gp(64, 4, 1);
  gemm_bt256<EPI_PHI_BIAS, false, true, false, true, false><<<gp, 512, 0, stream>>>(
      q, Wqb, bq, Ksum, Qb, 16384, 1024, 1024, 1024, 1024, 1024,
      0, 0, 0, 0, 0, 2, nullptr, nullptr, nullptr, nullptr);

  // 6. final: out[t,n] = (sum_d Qb[t,d]*G'[n,d]) / (Zraw[t]+1e-6) + bo[n].
  //    Zall points at Zraw (= Ksum+4096), sZb=4096 -> index abz*4096+row = t.
  dim3 gf(16, 4, 4);
  gemm_bt256<EPI_ZBIAS_F32, false, false, false, false, false><<<gf, 512, 0, stream>>>(
      Qb, Gp, bo, Ksum + 4096, out, 4096, 1024, 1024, 1024, 1024, 1024,
      4194304L, 1048576L, 4194304L, 4096L, 3, 2,
      nullptr, nullptr, nullptr, nullptr);
}

// Round 22
// 278.553 us; speedup vs baseline: 1.0050x; 1.0050x over previous
//
#include <hip/hip_runtime.h>

typedef unsigned short u16;
typedef unsigned int u32;
typedef unsigned long long u64;

typedef __attribute__((ext_vector_type(8))) short short8;   // 8 bf16 = 4 VGPRs
typedef __attribute__((ext_vector_type(4))) float floatx4;  // MFMA accumulator

__device__ __forceinline__ float b2f(u16 h) {
  u32 u = ((u32)h) << 16;
  return __builtin_bit_cast(float, u);
}
__device__ __forceinline__ u16 f2b(float f) {
  u32 u = __builtin_bit_cast(u32, f);
  u32 r = 0x7FFFu + ((u >> 16) & 1u);  // RNE
  return (u16)((u + r) >> 16);
}

// async global->LDS, 16B per lane. LDS dest = wave-uniform base + lane*16.
__device__ __forceinline__ void gl_lds16(const void* g, void* l) {
  __builtin_amdgcn_global_load_lds(
      (__attribute__((address_space(1))) void*)(u64)g,
      (__attribute__((address_space(3))) void*)(u32)(u64)l, 16, 0, 0);
}

enum { EPI_PHI_BIAS = 0, EPI_BIAS = 1, EPI_NONE = 2,
       EPI_ZBIAS_F32 = 3 };

// ==================== 256x256 kernel (ALL GEMMs) =============================
// R10-best structure: 256x256 tile, 8 waves (2M x 4N, 128x64 each, acc[8][4]),
// BK=64 K-tiles, 128B-contiguous staging rows, 2 x 64KB LDS buffers, 2 kstep/
// tile, one barrier per tile. (acc 128 regs + ~124 arch regs -> 2 waves/SIMD
// hard cap -> 1 block/CU is register- AND LDS-forced; schedule variants
// R9-R13 all null because no co-resident block can cover the barrier drains.)
// A_F32 (R14, R16): fp32->bf16 conversion fused into A-staging (no standalone
// fcvt passes). Depth-1 register prefetch, SINGLE rA set; packA AFTER
// kstep(kk1) so the 8 rA loads get ~2500cy of MFMA cover (R17: 67->62us).
//   top(t): loadA(t+1)->rA [8 float4]; stageB(t+1)->bufn [4 DMA]
//   kstep(kk0); kstep(kk1); packA(rA->bufn); vmcnt(0)+lgkmcnt(0); barrier
// R18 (KSUM): ksum_rows fused into the K-proj TRANS_OUT store pass (32-lane
// group shfl reduce + 1 atomicAdd per dloc; Ksum zeroed by wconv).
// R19 (ZDEN): zden fused into Q-proj epilogue (16-lane row-strip shfl reduce
// + 4 atomics/row into Zraw); final GEMM computes 1/(Zraw+1e-6) inline.
// (R20's K+V DUAL merge measured neutral; reverted to this best-measured.)
// LDS layout per matrix: 256 rows x 8 chunks of 16B, phys_chunk = c ^ (r&7);
// staging slot j: R=j>>3, c=(j&7)^(R&7); fragment reads ra*128+((q^(ra&7))*16),
// kk=1 = ^64 (uniform bank spread).
// Split-K / batch: abz = bz & abmask; kbase = (bz >> kshift) * K.
// B batched via sBb (final GEMM: G' = [4][1024][1024]).
// TRANS_OUT epilogue: two 128-col passes through sT[128][264] (fits LDS).
template<int EPI, bool TRANS_OUT, bool A_F32, bool KSUM, bool ZDEN>
__global__ __launch_bounds__(512, 2)
void gemm_bt256(const void* __restrict__ Ap, const u16* __restrict__ Bp0,
                const float* __restrict__ bias, const float* __restrict__ Zall,
                void* __restrict__ Cp,
                int M, int N, int K, int ldA, int ldB, int ldC,
                long sAb, long sBb, long sCb, long sZb, int abmask, int kshift)
{
  constexpr int TSTRIDE = 65536;                  // one K-tile buffer (A+B)
  constexpr int BOFF    = 32768;                  // B tile offset within buffer
  __shared__ char smem[2 * TSTRIDE];              // 128 KB -> 1 block/CU

  const int tid  = threadIdx.x;
  const int lane = tid & 63;
  const int wave = tid >> 6;
  const int wm = wave >> 2, wn = wave & 3;   // 2x4 waves, 128x64 each
  const int fl = lane & 15;
  const int q  = lane >> 4;
  const int r4 = q * 4;
  const int bm0 = blockIdx.x * 256, bn0 = blockIdx.y * 256;
  const int bz = blockIdx.z;
  const int abz = bz & abmask;
  const int kbase = (bz >> kshift) * K;

  const u16*   Ah = (const u16*)Ap   + (size_t)abz * sAb + kbase;
  const float* Af = (const float*)Ap + (size_t)abz * sAb + kbase;
  const u16*   Bh = Bp0 + (size_t)abz * sBb + kbase;

  // staging: per matrix 2048 16B LDS slots (256 rows x 8 swizzled chunks).
  const u16* gA[4]; const float* gAf[4]; const u16* gB[4]; int sL[4], dL[4];
  #pragma unroll
  for (int n = 0; n < 4; ++n) {
    int j = n * 512 + tid;                   // physical 16B slot
    int R = j >> 3, c = (j & 7) ^ (R & 7);
    if constexpr (A_F32) gAf[n] = Af + (size_t)(bm0 + R) * ldA + c * 8;
    else                 gA[n]  = Ah + (size_t)(bm0 + R) * ldA + c * 8;
    gB[n] = Bh + (size_t)(bn0 + R) * ldB + c * 8;
    sL[n] = (n * 512 + wave * 64) * 16;      // wave-uniform base (gl_lds)
    dL[n] = j * 16;                          // per-thread ds_write dest
  }

  // fragment LDS byte offsets (kk=0; kk=1 = ^64)
  int aoff[8], boff[4];
  #pragma unroll
  for (int i = 0; i < 8; ++i) {
    int ra = wm * 128 + i * 16 + fl;
    aoff[i] = ra * 128 + ((q ^ (ra & 7)) * 16);
  }
  #pragma unroll
  for (int i = 0; i < 4; ++i) {
    int rb = wn * 64 + i * 16 + fl;
    boff[i] = rb * 128 + ((q ^ (rb & 7)) * 16);
  }

  floatx4 zero = {0.f, 0.f, 0.f, 0.f};
  floatx4 acc[8][4];
  #pragma unroll
  for (int i = 0; i < 8; ++i)
    #pragma unroll
    for (int j = 0; j < 4; ++j) acc[i][j] = zero;

  auto stageB = [&](int t, char* base) {     // 4 gl_lds16, 128B rows
    #pragma unroll
    for (int n = 0; n < 4; ++n) gl_lds16(gB[n] + t * 64, base + BOFF + sL[n]);
  };
  auto stageA_dma = [&](int t, char* base) { // bf16-A path
    #pragma unroll
    for (int n = 0; n < 4; ++n) gl_lds16(gA[n] + t * 64, base + sL[n]);
  };

  float4 rA[8];                              // fp32-A path: in-flight A rows
  auto loadA = [&](int t) {
    #pragma unroll
    for (int n = 0; n < 4; ++n) {
      rA[2 * n]     = *(const float4*)(gAf[n] + t * 64);
      rA[2 * n + 1] = *(const float4*)(gAf[n] + t * 64 + 4);
    }
  };
  auto packA = [&](char* base) {             // truncate-pack (R1-proven)
    #pragma unroll
    for (int n = 0; n < 4; ++n) {
      const u32* xb = (const u32*)&rA[2 * n];
      const u32* yb = (const u32*)&rA[2 * n + 1];
      union { u32 w[4]; short8 s; } cv;
      cv.w[0] = __builtin_amdgcn_perm(xb[1], xb[0], 0x07060302u);
      cv.w[1] = __builtin_amdgcn_perm(xb[3], xb[2], 0x07060302u);
      cv.w[2] = __builtin_amdgcn_perm(yb[1], yb[0], 0x07060302u);
      cv.w[3] = __builtin_amdgcn_perm(yb[3], yb[2], 0x07060302u);
      *(short8*)(base + dL[n]) = cv.s;
    }
  };

  auto kstep = [&](const char* bufc, int xo) {  // xo = 0 (kk=0) or 64 (kk=1)
    short8 bF[4], aF[8];
    #pragma unroll
    for (int i = 0; i < 4; ++i) bF[i] = *(const short8*)(bufc + BOFF + (boff[i] ^ xo));
    #pragma unroll
    for (int i = 0; i < 8; ++i) aF[i] = *(const short8*)(bufc + (aoff[i] ^ xo));
    __builtin_amdgcn_s_setprio(1);
    #pragma unroll
    for (int mi = 0; mi < 8; ++mi)
      #pragma unroll
      for (int ni = 0; ni < 4; ++ni)
        acc[mi][ni] = __builtin_amdgcn_mfma_f32_16x16x32_bf16(
            aF[mi], bF[ni], acc[mi][ni], 0, 0, 0);
    __builtin_amdgcn_s_setprio(0);
  };

  const int NT = K >> 6;                     // 16 (K=1024) or 4 (G, K=256)
  if constexpr (A_F32) {
    loadA(0); stageB(0, smem);
    asm volatile("s_waitcnt vmcnt(4)" ::: "memory");   // 8 A loads (oldest)
    packA(smem);
    asm volatile("s_waitcnt vmcnt(0) lgkmcnt(0)\ns_barrier" ::: "memory");
    int cur = 0;
    for (int t = 0; t < NT; ++t) {
      const bool pf = t + 1 < NT;
      const char* bufc = smem + cur;
      char* bufn = smem + (cur ^ TSTRIDE);
      if (pf) { loadA(t + 1); stageB(t + 1, bufn); }
      kstep(bufc, 0);
      kstep(bufc, 64);
      if (pf) {
        packA(bufn);                         // rA covered by both ksteps
        asm volatile("s_waitcnt vmcnt(0) lgkmcnt(0)\ns_barrier" ::: "memory");
      }
      cur ^= TSTRIDE;
    }
  } else {
    stageA_dma(0, smem); stageB(0, smem);
    asm volatile("s_waitcnt vmcnt(0)\ns_barrier" ::: "memory");
    int cur = 0;
    for (int t = 0; t < NT; ++t) {
      if (t + 1 < NT) {
        stageA_dma(t + 1, smem + (cur ^ TSTRIDE));
        stageB(t + 1, smem + (cur ^ TSTRIDE));
      }
      const char* bufc = smem + cur;
      kstep(bufc, 0);
      kstep(bufc, 64);
      if (t + 1 < NT)
        asm volatile("s_waitcnt vmcnt(0) lgkmcnt(0)\ns_barrier" ::: "memory");
      cur ^= TSTRIDE;
    }
  }

  if constexpr (!TRANS_OUT) {
    float ksc[4];                            // ZDEN: Ksum[col] per ni (L2-hot)
    if constexpr (ZDEN) {
      #pragma unroll
      for (int ni = 0; ni < 4; ++ni)
        ksc[ni] = Zall[bn0 + wn * 64 + ni * 16 + fl];   // Zall = Ksum here
    }
    #pragma unroll
    for (int mi = 0; mi < 8; ++mi) {
      #pragma unroll
      for (int r = 0; r < 4; ++r) {
        int row = bm0 + wm * 128 + mi * 16 + r4 + r;
        float zv = 0.f, zs = 0.f;
        if constexpr (EPI == EPI_ZBIAS_F32)
          zv = 1.0f / (Zall[(size_t)abz * sZb + row] + 1e-6f);
        #pragma unroll
        for (int ni = 0; ni < 4; ++ni) {
          int col = bn0 + wn * 64 + ni * 16 + fl;
          float vv = acc[mi][ni][r];
          if constexpr (EPI == EPI_PHI_BIAS) {
            vv += bias[col];
            vv = __expf(-0.5f * vv * vv);
          }
          if constexpr (EPI == EPI_ZBIAS_F32) {
            ((float*)Cp)[(size_t)bz * sCb + (size_t)row * ldC + col] =
                vv * zv + bias[col];
          } else {
            ((u16*)Cp)[(size_t)bz * sCb + (size_t)row * ldC + col] = f2b(vv);
          }
          if constexpr (ZDEN) zs += vv * ksc[ni];
        }
        if constexpr (ZDEN) {
          #pragma unroll
          for (int off = 1; off < 16; off <<= 1)
            zs += __shfl_xor(zs, off, 64);   // within 16-lane row group
          if (fl == 0)
            atomicAdd((float*)&Zall[4096 + row], zs);  // Zraw = Ksum+4096
        }
      }
    }
  } else {
    // two passes of 128 d-cols through sT[128][264]; coalesced 16B stores
    // into C = [4][N(d)][4096(t)] bf16 (256-row tile never crosses a batch).
    u16* sT = (u16*)smem;                    // 128*264*2 = 67584 <= 128K
    #pragma unroll
    for (int p = 0; p < 2; ++p) {
      __syncthreads();                       // p=0: drains K-loop (all cnts)
      if ((wn >> 1) == p) {
        #pragma unroll
        for (int mi = 0; mi < 8; ++mi) {
          #pragma unroll
          for (int ni = 0; ni < 4; ++ni) {
            int colL = wn * 64 + ni * 16 + fl;       // in [p*128, p*128+128)
            int row0 = wm * 128 + mi * 16 + r4;
            float bcol = bias[bn0 + colL];
            ushort4 h;
            #pragma unroll
            for (int r = 0; r < 4; ++r) {
              float vv = acc[mi][ni][r] + bcol;
              if constexpr (EPI == EPI_PHI_BIAS) vv = __expf(-0.5f * vv * vv);
              ((u16*)&h)[r] = f2b(vv);
            }
            *(ushort4*)(sT + (colL - p * 128) * 264 + row0) = h;
          }
        }
      }
      __syncthreads();
      #pragma unroll
      for (int i = 0; i < 8; ++i) {
        int c = tid + i * 512;               // 4096 x 16B chunks
        int dloc = c >> 5, t8 = (c & 31) * 8;
        int4 vv = *(const int4*)(sT + dloc * 264 + t8);
        int gd = bn0 + p * 128 + dloc;
        int gt = bm0 + t8;
        int batch = gt >> 12, tt = gt & 4095;
        *(int4*)((u16*)Cp + ((size_t)batch * N + gd) * 4096 + tt) = vv;
        if constexpr (KSUM) {
          // fused ksum: chunk sum -> 32-lane-group reduce -> one atomicAdd.
          const u16* hh = (const u16*)&vv;
          float s8 = 0.f;
          #pragma unroll
          for (int j = 0; j < 8; ++j) s8 += b2f(hh[j]);
          #pragma unroll
          for (int off = 1; off < 32; off <<= 1)
            s8 += __shfl_xor(s8, off, 64);   // offs<32: stays in 32-lane half
          if ((lane & 31) == 0)
            atomicAdd((float*)&Zall[(size_t)batch * 1024 + gd], s8);
        }
      }
    }
  }
}

// weights -> bf16; also zero Ksum[4096] + Zraw[16384] (f32) for fused passes.
__global__ __launch_bounds__(256)
void wconv(const float* __restrict__ w0, const float* __restrict__ w1,
           const float* __restrict__ w2, const float* __restrict__ w3,
           u16* __restrict__ dst, float* __restrict__ Ksum) {
  unsigned e = blockIdx.x * 256 + threadIdx.x;
  if (e < 4096) Ksum[e] = 0.f;
  if (e < 16384) Ksum[4096 + e] = 0.f;       // Zraw
  int mat = e >> 18;
  size_t off = (size_t)(e & 262143) * 4;
  const float* src = mat == 0 ? w0 : mat == 1 ? w1 : mat == 2 ? w2 : w3;
  float4 v = *(const float4*)(src + off);
  ushort4 h;
  h.x = f2b(v.x); h.y = f2b(v.y); h.z = f2b(v.z); h.w = f2b(v.w);
  *(ushort4*)(dst + (size_t)mat * 1048576 + off) = h;
}

// out[i] = round(sum over 4 K-slices of bf16 partials), 4M elems, slice stride 4M
__global__ __launch_bounds__(256)
void reduce4(const u16* __restrict__ P, u16* __restrict__ out) {
  size_t i = ((size_t)blockIdx.x * 256 + threadIdx.x) * 8;
  int4 a = *(const int4*)(P + i);
  int4 b = *(const int4*)(P + i + 4194304);
  int4 c = *(const int4*)(P + i + 8388608);
  int4 d = *(const int4*)(P + i + 12582912);
  const u16* ha = (const u16*)&a; const u16* hb = (const u16*)&b;
  const u16* hc = (const u16*)&c; const u16* hd = (const u16*)&d;
  ushort4 o0, o1;
  #pragma unroll
  for (int j = 0; j < 8; ++j) {
    float s = b2f(ha[j]) + b2f(hb[j]) + b2f(hc[j]) + b2f(hd[j]);
    ((u16*)(j < 4 ? &o0 : &o1))[j & 3] = f2b(s);
  }
  *(ushort4*)(out + i) = o0;
  *(ushort4*)(out + i + 4) = o1;
}

extern "C" void kernel_launch(void* const* d_in, const int* in_sizes, int n_in,
                              void* d_out, int out_size, void* d_ws, size_t ws_size,
                              hipStream_t stream) {
  const float* q  = (const float*)d_in[0];
  const float* k  = (const float*)d_in[1];
  const float* v  = (const float*)d_in[2];
  const float* Wq = (const float*)d_in[3];
  const float* bq = (const float*)d_in[4];
  const float* Wk = (const float*)d_in[5];
  const float* bk = (const float*)d_in[6];
  const float* Wv = (const float*)d_in[7];
  const float* bv = (const float*)d_in[8];
  const float* Wo = (const float*)d_in[9];
  const float* bo = (const float*)d_in[10];
  float* out = (float*)d_out;

  // workspace layout (~112.1 MiB), aliasing chain (stream-ordered):
  u16* Wqb = (u16*)d_ws;                 // 4x 1024x1024 bf16 = 8 MiB
  u16* Wkb = Wqb + 1048576;
  u16* Wvb = Wkb + 1048576;
  u16* Wob = Wvb + 1048576;
  u16* Qb  = Wob + 1048576;              // [16384][1024] bf16, 32 MiB
  u16* KT  = Qb  + 16777216;             // [4][1024][4096] bf16, 32 MiB
  u16* VT  = KT  + 16777216;             // [4][1024][4096] bf16, 32 MiB
  u16* KVr = VT  + 16777216;             // [4][1024(d)][1024(l)] bf16, 8 MiB
  float* Ksum = (float*)(KVr + 4194304); // [4][1024] f32; Zraw = Ksum+4096
  // region reuse (each write strictly after the prior reader finishes):
  u16* Pkv = Qb;   // S2 split-K partials; dead after its reduce4 (Qproj later)
  u16* Pg  = VT;   // G split-K partials (VT dead after S2)
  u16* Gp  = KT;   // G' [4][1024(n)][1024(d)] (KT dead after S2)

  // 1. weights -> bf16 + Ksum/Zraw zero-init
  wconv<<<4096, 256, 0, stream>>>(Wq, Wk, Wv, Wo, Wqb, Ksum);

  // 2. K projection: KT[b][d][t] = phi(k Wk^T + bk), fp32-A fused, trans out,
  //    KSUM fused (atomics into Ksum).
  dim3 gp(64, 4, 1);
  gemm_bt256<EPI_PHI_BIAS, true, true, true, false><<<gp, 512, 0, stream>>>(
      k, Wkb, bk, Ksum, KT, 16384, 1024, 1024, 1024, 1024, 0,
      0, 0, 0, 0, 0, 2);

  // 3. V projection (fp32-A fused)
  gemm_bt256<EPI_BIAS, true, true, false, false><<<gp, 512, 0, stream>>>(
      v, Wvb, bv, nullptr, VT, 16384, 1024, 1024, 1024, 1024, 0,
      0, 0, 0, 0, 0, 2);

  // 4. S2: KVr[d,l] = sum_t KT[d,t]*VT[l,t], split-K x4 (z = kslice*4+batch)
  dim3 g2(4, 4, 16);
  gemm_bt256<EPI_NONE, false, false, false, false><<<g2, 512, 0, stream>>>(
      KT, VT, nullptr, nullptr, Pkv, 1024, 1024, 1024, 4096, 4096, 1024,
      4194304L, 4194304L, 1048576L, 0, 3, 2);
  reduce4<<<2048, 256, 0, stream>>>(Pkv, KVr);

  // 5. G'[n,d] = sum_l Wob[n,l]*KVr[d,l], split-K x4 (K=256/slice)
  dim3 gg(4, 4, 16);
  gemm_bt256<EPI_NONE, false, false, false, false><<<gg, 512, 0, stream>>>(
      Wob, KVr, nullptr, nullptr, Pg, 1024, 1024, 256, 1024, 1024, 1024,
      0L, 1048576L, 1048576L, 0, 3, 2);
  reduce4<<<2048, 256, 0, stream>>>(Pg, Gp);

  // 6. Q projection (fp32-A fused; ZDEN fused: zs(row) atomics into Zraw;
  //    Ksum complete — K-proj stream-ordered earlier).
  gemm_bt256<EPI_PHI_BIAS, false, true, false, true><<<gp, 512, 0, stream>>>(
      q, Wqb, bq, Ksum, Qb, 16384, 1024, 1024, 1024, 1024, 1024,
      0, 0, 0, 0, 0, 2);

  // 7. final: out[t,n] = (sum_d Qb[t,d]*G'[n,d]) / (Zraw[t]+1e-6) + bo[n].
  //    Zall points at Zraw (= Ksum+4096), sZb=4096 -> index abz*4096+row = t.
  dim3 gf(16, 4, 4);
  gemm_bt256<EPI_ZBIAS_F32, false, false, false, false><<<gf, 512, 0, stream>>>(
      Qb, Gp, bo, Ksum + 4096, out, 4096, 1024, 1024, 1024, 1024, 1024,
      4194304L, 1048576L, 4194304L, 4096L, 3, 2);
}

// Round 26
// 276.835 us; speedup vs baseline: 1.0112x; 1.0062x over previous
//
#include <hip/hip_runtime.h>

typedef unsigned short u16;
typedef unsigned int u32;
typedef unsigned long long u64;

typedef __attribute__((ext_vector_type(8))) short short8;   // 8 bf16 = 4 VGPRs
typedef __attribute__((ext_vector_type(4))) float floatx4;  // MFMA accumulator

__device__ __forceinline__ float b2f(u16 h) {
  u32 u = ((u32)h) << 16;
  return __builtin_bit_cast(float, u);
}
__device__ __forceinline__ u16 f2b(float f) {
  u32 u = __builtin_bit_cast(u32, f);
  u32 r = 0x7FFFu + ((u >> 16) & 1u);  // RNE
  return (u16)((u + r) >> 16);
}

// async global->LDS, 16B per lane. LDS dest = wave-uniform base + lane*16.
__device__ __forceinline__ void gl_lds16(const void* g, void* l) {
  __builtin_amdgcn_global_load_lds(
      (__attribute__((address_space(1))) void*)(u64)g,
      (__attribute__((address_space(3))) void*)(u32)(u64)l, 16, 0, 0);
}

enum { EPI_PHI_BIAS = 0, EPI_BIAS = 1, EPI_NONE = 2,
       EPI_ZBIAS_F32 = 3 };

// ==================== 256x256 kernel (ALL GEMMs) =============================
// R10-best structure: 256x256 tile, 8 waves (2M x 4N, 128x64 each, acc[8][4]),
// BK=64 K-tiles, 128B-contiguous staging rows, 2 x 64KB LDS buffers, 2 kstep/
// tile, one barrier per tile. (acc 128 regs + ~124 arch regs -> 2 waves/SIMD
// hard cap -> 1 block/CU is register- AND LDS-forced; schedule variants
// R9-R13 all null because no co-resident block can cover the barrier drains.)
// A_F32 (R14, R16): fp32->bf16 conversion fused into A-staging (no standalone
// fcvt passes). Depth-1 register prefetch, SINGLE rA set; packA AFTER
// kstep(kk1) so the 8 rA loads get ~2500cy of MFMA cover (R17: 67->62us).
//   top(t): loadA(t+1)->rA [8 float4]; stageB(t+1)->bufn [4 DMA]
//   kstep(kk0); kstep(kk1); packA(rA->bufn); vmcnt(0)+lgkmcnt(0); barrier
// R18 (KSUM): ksum_rows fused into the K-proj TRANS_OUT store pass (32-lane
// group shfl reduce + 1 atomicAdd per dloc; Ksum zeroed by wconv).
// R19 (ZDEN): zden fused into Q-proj epilogue (16-lane row-strip shfl reduce
// + 4 atomics/row into Zraw); final GEMM computes 1/(Zraw+1e-6) inline.
// (R20's K+V DUAL merge measured neutral; reverted to this best-measured.)
// LDS layout per matrix: 256 rows x 8 chunks of 16B, phys_chunk = c ^ (r&7);
// staging slot j: R=j>>3, c=(j&7)^(R&7); fragment reads ra*128+((q^(ra&7))*16),
// kk=1 = ^64 (uniform bank spread).
// Split-K / batch: abz = bz & abmask; kbase = (bz >> kshift) * K.
// B batched via sBb (final GEMM: G' = [4][1024][1024]).
// TRANS_OUT epilogue: two 128-col passes through sT[128][264] (fits LDS).
template<int EPI, bool TRANS_OUT, bool A_F32, bool KSUM, bool ZDEN>
__global__ __launch_bounds__(512, 2)
void gemm_bt256(const void* __restrict__ Ap, const u16* __restrict__ Bp0,
                const float* __restrict__ bias, const float* __restrict__ Zall,
                void* __restrict__ Cp,
                int M, int N, int K, int ldA, int ldB, int ldC,
                long sAb, long sBb, long sCb, long sZb, int abmask, int kshift)
{
  constexpr int TSTRIDE = 65536;                  // one K-tile buffer (A+B)
  constexpr int BOFF    = 32768;                  // B tile offset within buffer
  __shared__ char smem[2 * TSTRIDE];              // 128 KB -> 1 block/CU

  const int tid  = threadIdx.x;
  const int lane = tid & 63;
  const int wave = tid >> 6;
  const int wm = wave >> 2, wn = wave & 3;   // 2x4 waves, 128x64 each
  const int fl = lane & 15;
  const int q  = lane >> 4;
  const int r4 = q * 4;
  const int bm0 = blockIdx.x * 256, bn0 = blockIdx.y * 256;
  const int bz = blockIdx.z;
  const int abz = bz & abmask;
  const int kbase = (bz >> kshift) * K;

  const u16*   Ah = (const u16*)Ap   + (size_t)abz * sAb + kbase;
  const float* Af = (const float*)Ap + (size_t)abz * sAb + kbase;
  const u16*   Bh = Bp0 + (size_t)abz * sBb + kbase;

  // staging: per matrix 2048 16B LDS slots (256 rows x 8 swizzled chunks).
  const u16* gA[4]; const float* gAf[4]; const u16* gB[4]; int sL[4], dL[4];
  #pragma unroll
  for (int n = 0; n < 4; ++n) {
    int j = n * 512 + tid;                   // physical 16B slot
    int R = j >> 3, c = (j & 7) ^ (R & 7);
    if constexpr (A_F32) gAf[n] = Af + (size_t)(bm0 + R) * ldA + c * 8;
    else                 gA[n]  = Ah + (size_t)(bm0 + R) * ldA + c * 8;
    gB[n] = Bh + (size_t)(bn0 + R) * ldB + c * 8;
    sL[n] = (n * 512 + wave * 64) * 16;      // wave-uniform base (gl_lds)
    dL[n] = j * 16;                          // per-thread ds_write dest
  }

  // fragment LDS byte offsets (kk=0; kk=1 = ^64)
  int aoff[8], boff[4];
  #pragma unroll
  for (int i = 0; i < 8; ++i) {
    int ra = wm * 128 + i * 16 + fl;
    aoff[i] = ra * 128 + ((q ^ (ra & 7)) * 16);
  }
  #pragma unroll
  for (int i = 0; i < 4; ++i) {
    int rb = wn * 64 + i * 16 + fl;
    boff[i] = rb * 128 + ((q ^ (rb & 7)) * 16);
  }

  floatx4 zero = {0.f, 0.f, 0.f, 0.f};
  floatx4 acc[8][4];
  #pragma unroll
  for (int i = 0; i < 8; ++i)
    #pragma unroll
    for (int j = 0; j < 4; ++j) acc[i][j] = zero;

  auto stageB = [&](int t, char* base) {     // 4 gl_lds16, 128B rows
    #pragma unroll
    for (int n = 0; n < 4; ++n) gl_lds16(gB[n] + t * 64, base + BOFF + sL[n]);
  };
  auto stageA_dma = [&](int t, char* base) { // bf16-A path
    #pragma unroll
    for (int n = 0; n < 4; ++n) gl_lds16(gA[n] + t * 64, base + sL[n]);
  };

  float4 rA[8];                              // fp32-A path: in-flight A rows
  auto loadA = [&](int t) {
    #pragma unroll
    for (int n = 0; n < 4; ++n) {
      rA[2 * n]     = *(const float4*)(gAf[n] + t * 64);
      rA[2 * n + 1] = *(const float4*)(gAf[n] + t * 64 + 4);
    }
  };
  auto packA = [&](char* base) {             // truncate-pack (R1-proven)
    #pragma unroll
    for (int n = 0; n < 4; ++n) {
      const u32* xb = (const u32*)&rA[2 * n];
      const u32* yb = (const u32*)&rA[2 * n + 1];
      union { u32 w[4]; short8 s; } cv;
      cv.w[0] = __builtin_amdgcn_perm(xb[1], xb[0], 0x07060302u);
      cv.w[1] = __builtin_amdgcn_perm(xb[3], xb[2], 0x07060302u);
      cv.w[2] = __builtin_amdgcn_perm(yb[1], yb[0], 0x07060302u);
      cv.w[3] = __builtin_amdgcn_perm(yb[3], yb[2], 0x07060302u);
      *(short8*)(base + dL[n]) = cv.s;
    }
  };

  auto kstep = [&](const char* bufc, int xo) {  // xo = 0 (kk=0) or 64 (kk=1)
    short8 bF[4], aF[8];
    #pragma unroll
    for (int i = 0; i < 4; ++i) bF[i] = *(const short8*)(bufc + BOFF + (boff[i] ^ xo));
    #pragma unroll
    for (int i = 0; i < 8; ++i) aF[i] = *(const short8*)(bufc + (aoff[i] ^ xo));
    __builtin_amdgcn_s_setprio(1);
    #pragma unroll
    for (int mi = 0; mi < 8; ++mi)
      #pragma unroll
      for (int ni = 0; ni < 4; ++ni)
        acc[mi][ni] = __builtin_amdgcn_mfma_f32_16x16x32_bf16(
            aF[mi], bF[ni], acc[mi][ni], 0, 0, 0);
    __builtin_amdgcn_s_setprio(0);
  };

  const int NT = K >> 6;                     // 16 (K=1024) or 4 (G, K=256)
  if constexpr (A_F32) {
    loadA(0); stageB(0, smem);
    asm volatile("s_waitcnt vmcnt(4)" ::: "memory");   // 8 A loads (oldest)
    packA(smem);
    asm volatile("s_waitcnt vmcnt(0) lgkmcnt(0)\ns_barrier" ::: "memory");
    int cur = 0;
    for (int t = 0; t < NT; ++t) {
      const bool pf = t + 1 < NT;
      const char* bufc = smem + cur;
      char* bufn = smem + (cur ^ TSTRIDE);
      if (pf) { loadA(t + 1); stageB(t + 1, bufn); }
      kstep(bufc, 0);
      kstep(bufc, 64);
      if (pf) {
        packA(bufn);                         // rA covered by both ksteps
        asm volatile("s_waitcnt vmcnt(0) lgkmcnt(0)\ns_barrier" ::: "memory");
      }
      cur ^= TSTRIDE;
    }
  } else {
    stageA_dma(0, smem); stageB(0, smem);
    asm volatile("s_waitcnt vmcnt(0)\ns_barrier" ::: "memory");
    int cur = 0;
    for (int t = 0; t < NT; ++t) {
      if (t + 1 < NT) {
        stageA_dma(t + 1, smem + (cur ^ TSTRIDE));
        stageB(t + 1, smem + (cur ^ TSTRIDE));
      }
      const char* bufc = smem + cur;
      kstep(bufc, 0);
      kstep(bufc, 64);
      if (t + 1 < NT)
        asm volatile("s_waitcnt vmcnt(0) lgkmcnt(0)\ns_barrier" ::: "memory");
      cur ^= TSTRIDE;
    }
  }

  if constexpr (!TRANS_OUT) {
    float ksc[4];                            // ZDEN: Ksum[col] per ni (L2-hot)
    if constexpr (ZDEN) {
      #pragma unroll
      for (int ni = 0; ni < 4; ++ni)
        ksc[ni] = Zall[bn0 + wn * 64 + ni * 16 + fl];   // Zall = Ksum here
    }
    #pragma unroll
    for (int mi = 0; mi < 8; ++mi) {
      #pragma unroll
      for (int r = 0; r < 4; ++r) {
        int row = bm0 + wm * 128 + mi * 16 + r4 + r;
        float zv = 0.f, zs = 0.f;
        if constexpr (EPI == EPI_ZBIAS_F32)
          zv = 1.0f / (Zall[(size_t)abz * sZb + row] + 1e-6f);
        #pragma unroll
        for (int ni = 0; ni < 4; ++ni) {
          int col = bn0 + wn * 64 + ni * 16 + fl;
          float vv = acc[mi][ni][r];
          if constexpr (EPI == EPI_PHI_BIAS) {
            vv += bias[col];
            vv = __expf(-0.5f * vv * vv);
          }
          if constexpr (EPI == EPI_ZBIAS_F32) {
            ((float*)Cp)[(size_t)bz * sCb + (size_t)row * ldC + col] =
                vv * zv + bias[col];
          } else {
            ((u16*)Cp)[(size_t)bz * sCb + (size_t)row * ldC + col] = f2b(vv);
          }
          if constexpr (ZDEN) zs += vv * ksc[ni];
        }
        if constexpr (ZDEN) {
          #pragma unroll
          for (int off = 1; off < 16; off <<= 1)
            zs += __shfl_xor(zs, off, 64);   // within 16-lane row group
          if (fl == 0)
            atomicAdd((float*)&Zall[4096 + row], zs);  // Zraw = Ksum+4096
        }
      }
    }
  } else {
    // two passes of 128 d-cols through sT[128][264]; coalesced 16B stores
    // into C = [4][N(d)][4096(t)] bf16 (256-row tile never crosses a batch).
    u16* sT = (u16*)smem;                    // 128*264*2 = 67584 <= 128K
    #pragma unroll
    for (int p = 0; p < 2; ++p) {
      __syncthreads();                       // p=0: drains K-loop (all cnts)
      if ((wn >> 1) == p) {
        #pragma unroll
        for (int mi = 0; mi < 8; ++mi) {
          #pragma unroll
          for (int ni = 0; ni < 4; ++ni) {
            int colL = wn * 64 + ni * 16 + fl;       // in [p*128, p*128+128)
            int row0 = wm * 128 + mi * 16 + r4;
            float bcol = bias[bn0 + colL];
            ushort4 h;
            #pragma unroll
            for (int r = 0; r < 4; ++r) {
              float vv = acc[mi][ni][r] + bcol;
              if constexpr (EPI == EPI_PHI_BIAS) vv = __expf(-0.5f * vv * vv);
              ((u16*)&h)[r] = f2b(vv);
            }
            *(ushort4*)(sT + (colL - p * 128) * 264 + row0) = h;
          }
        }
      }
      __syncthreads();
      #pragma unroll
      for (int i = 0; i < 8; ++i) {
        int c = tid + i * 512;               // 4096 x 16B chunks
        int dloc = c >> 5, t8 = (c & 31) * 8;
        int4 vv = *(const int4*)(sT + dloc * 264 + t8);
        int gd = bn0 + p * 128 + dloc;
        int gt = bm0 + t8;
        int batch = gt >> 12, tt = gt & 4095;
        *(int4*)((u16*)Cp + ((size_t)batch * N + gd) * 4096 + tt) = vv;
        if constexpr (KSUM) {
          // fused ksum: chunk sum -> 32-lane-group reduce -> one atomicAdd.
          const u16* hh = (const u16*)&vv;
          float s8 = 0.f;
          #pragma unroll
          for (int j = 0; j < 8; ++j) s8 += b2f(hh[j]);
          #pragma unroll
          for (int off = 1; off < 32; off <<= 1)
            s8 += __shfl_xor(s8, off, 64);   // offs<32: stays in 32-lane half
          if ((lane & 31) == 0)
            atomicAdd((float*)&Zall[(size_t)batch * 1024 + gd], s8);
        }
      }
    }
  }
}

// weights -> bf16; also zero Ksum[4096] + Zraw[16384] (f32) for fused passes.
__global__ __launch_bounds__(256)
void wconv(const float* __restrict__ w0, const float* __restrict__ w1,
           const float* __restrict__ w2, const float* __restrict__ w3,
           u16* __restrict__ dst, float* __restrict__ Ksum) {
  unsigned e = blockIdx.x * 256 + threadIdx.x;
  if (e < 4096) Ksum[e] = 0.f;
  if (e < 16384) Ksum[4096 + e] = 0.f;       // Zraw
  int mat = e >> 18;
  size_t off = (size_t)(e & 262143) * 4;
  const float* src = mat == 0 ? w0 : mat == 1 ? w1 : mat == 2 ? w2 : w3;
  float4 v = *(const float4*)(src + off);
  ushort4 h;
  h.x = f2b(v.x); h.y = f2b(v.y); h.z = f2b(v.z); h.w = f2b(v.w);
  *(ushort4*)(dst + (size_t)mat * 1048576 + off) = h;
}

// out[i] = round(sum over 4 K-slices of bf16 partials), 4M elems, slice stride 4M
__global__ __launch_bounds__(256)
void reduce4(const u16* __restrict__ P, u16* __restrict__ out) {
  size_t i = ((size_t)blockIdx.x * 256 + threadIdx.x) * 8;
  int4 a = *(const int4*)(P + i);
  int4 b = *(const int4*)(P + i + 4194304);
  int4 c = *(const int4*)(P + i + 8388608);
  int4 d = *(const int4*)(P + i + 12582912);
  const u16* ha = (const u16*)&a; const u16* hb = (const u16*)&b;
  const u16* hc = (const u16*)&c; const u16* hd = (const u16*)&d;
  ushort4 o0, o1;
  #pragma unroll
  for (int j = 0; j < 8; ++j) {
    float s = b2f(ha[j]) + b2f(hb[j]) + b2f(hc[j]) + b2f(hd[j]);
    ((u16*)(j < 4 ? &o0 : &o1))[j & 3] = f2b(s);
  }
  *(ushort4*)(out + i) = o0;
  *(ushort4*)(out + i + 4) = o1;
}

extern "C" void kernel_launch(void* const* d_in, const int* in_sizes, int n_in,
                              void* d_out, int out_size, void* d_ws, size_t ws_size,
                              hipStream_t stream) {
  const float* q  = (const float*)d_in[0];
  const float* k  = (const float*)d_in[1];
  const float* v  = (const float*)d_in[2];
  const float* Wq = (const float*)d_in[3];
  const float* bq = (const float*)d_in[4];
  const float* Wk = (const float*)d_in[5];
  const float* bk = (const float*)d_in[6];
  const float* Wv = (const float*)d_in[7];
  const float* bv = (const float*)d_in[8];
  const float* Wo = (const float*)d_in[9];
  const float* bo = (const float*)d_in[10];
  float* out = (float*)d_out;

  // workspace layout (~112.1 MiB), aliasing chain (stream-ordered):
  u16* Wqb = (u16*)d_ws;                 // 4x 1024x1024 bf16 = 8 MiB
  u16* Wkb = Wqb + 1048576;
  u16* Wvb = Wkb + 1048576;
  u16* Wob = Wvb + 1048576;
  u16* Qb  = Wob + 1048576;              // [16384][1024] bf16, 32 MiB
  u16* KT  = Qb  + 16777216;             // [4][1024][4096] bf16, 32 MiB
  u16* VT  = KT  + 16777216;             // [4][1024][4096] bf16, 32 MiB
  u16* KVr = VT  + 16777216;             // [4][1024(d)][1024(l)] bf16, 8 MiB
  float* Ksum = (float*)(KVr + 4194304); // [4][1024] f32; Zraw = Ksum+4096
  // region reuse (each write strictly after the prior reader finishes):
  u16* Pkv = Qb;   // S2 split-K partials; dead after its reduce4 (Qproj later)
  u16* Pg  = VT;   // G split-K partials (VT dead after S2)
  u16* Gp  = KT;   // G' [4][1024(n)][1024(d)] (KT dead after S2)

  // 1. weights -> bf16 + Ksum/Zraw zero-init
  wconv<<<4096, 256, 0, stream>>>(Wq, Wk, Wv, Wo, Wqb, Ksum);

  // 2. K projection: KT[b][d][t] = phi(k Wk^T + bk), fp32-A fused, trans out,
  //    KSUM fused (atomics into Ksum).
  dim3 gp(64, 4, 1);
  gemm_bt256<EPI_PHI_BIAS, true, true, true, false><<<gp, 512, 0, stream>>>(
      k, Wkb, bk, Ksum, KT, 16384, 1024, 1024, 1024, 1024, 0,
      0, 0, 0, 0, 0, 2);

  // 3. V projection (fp32-A fused)
  gemm_bt256<EPI_BIAS, true, true, false, false><<<gp, 512, 0, stream>>>(
      v, Wvb, bv, nullptr, VT, 16384, 1024, 1024, 1024, 1024, 0,
      0, 0, 0, 0, 0, 2);

  // 4. S2: KVr[d,l] = sum_t KT[d,t]*VT[l,t], split-K x4 (z = kslice*4+batch)
  dim3 g2(4, 4, 16);
  gemm_bt256<EPI_NONE, false, false, false, false><<<g2, 512, 0, stream>>>(
      KT, VT, nullptr, nullptr, Pkv, 1024, 1024, 1024, 4096, 4096, 1024,
      4194304L, 4194304L, 1048576L, 0, 3, 2);
  reduce4<<<2048, 256, 0, stream>>>(Pkv, KVr);

  // 5. G'[n,d] = sum_l Wob[n,l]*KVr[d,l], split-K x4 (K=256/slice)
  dim3 gg(4, 4, 16);
  gemm_bt256<EPI_NONE, false, false, false, false><<<gg, 512, 0, stream>>>(
      Wob, KVr, nullptr, nullptr, Pg, 1024, 1024, 256, 1024, 1024, 1024,
      0L, 1048576L, 1048576L, 0, 3, 2);
  reduce4<<<2048, 256, 0, stream>>>(Pg, Gp);

  // 6. Q projection (fp32-A fused; ZDEN fused: zs(row) atomics into Zraw;
  //    Ksum complete — K-proj stream-ordered earlier).
  gemm_bt256<EPI_PHI_BIAS, false, true, false, true><<<gp, 512, 0, stream>>>(
      q, Wqb, bq, Ksum, Qb, 16384, 1024, 1024, 1024, 1024, 1024,
      0, 0, 0, 0, 0, 2);

  // 7. final: out[t,n] = (sum_d Qb[t,d]*G'[n,d]) / (Zraw[t]+1e-6) + bo[n].
  //    Zall points at Zraw (= Ksum+4096), sZb=4096 -> index abz*4096+row = t.
  dim3 gf(16, 4, 4);
  gemm_bt256<EPI_ZBIAS_F32, false, false, false, false><<<gf, 512, 0, stream>>>(
      Qb, Gp, bo, Ksum + 4096, out, 4096, 1024, 1024, 1024, 1024, 1024,
      4194304L, 1048576L, 4194304L, 4096L, 3, 2);
}